// Round 2
// baseline (722.326 us; speedup 1.0000x reference)
//
#include <hip/hip_runtime.h>

#define NNODES 50000
#define NEDGES 500000
#define DIN 128
#define DHID 256

__global__ void k_zero_i32(int* __restrict__ p, int n) {
  int i = blockIdx.x * blockDim.x + threadIdx.x;
  if (i < n) p[i] = 0;
}

__global__ void k_hist(const int* __restrict__ dst, int* __restrict__ deg, int e) {
  int i = blockIdx.x * blockDim.x + threadIdx.x;
  if (i < e) atomicAdd(&deg[dst[i]], 1);
}

__global__ void k_dinv(const int* __restrict__ deg, float* __restrict__ dinv, int n) {
  int i = blockIdx.x * blockDim.x + threadIdx.x;
  if (i < n) dinv[i] = rsqrtf((float)deg[i] + 1.0f);  // +1 = self loop
}

// exclusive scan of deg[0..n) -> row_ptr[0..n], single workgroup
__global__ __launch_bounds__(1024) void k_scan(const int* __restrict__ deg,
                                               int* __restrict__ row_ptr, int n) {
  __shared__ int part[1024];
  const int t = threadIdx.x;
  const int C = (n + 1023) >> 10;
  const int base = t * C;
  int sum = 0;
  for (int j = 0; j < C; ++j) {
    int idx = base + j;
    if (idx < n) sum += deg[idx];
  }
  part[t] = sum;
  __syncthreads();
  for (int off = 1; off < 1024; off <<= 1) {
    int v = (t >= off) ? part[t - off] : 0;
    __syncthreads();
    part[t] += v;
    __syncthreads();
  }
  int run = (t == 0) ? 0 : part[t - 1];
  for (int j = 0; j < C; ++j) {
    int idx = base + j;
    if (idx < n) { row_ptr[idx] = run; run += deg[idx]; }
  }
  if (t == 1023) row_ptr[n] = part[1023];
}

__global__ void k_fill(const int* __restrict__ src, const int* __restrict__ dst,
                       const float* __restrict__ dinv, const int* __restrict__ row_ptr,
                       int* __restrict__ cursor, int* __restrict__ csr_src,
                       float* __restrict__ csr_norm, int e) {
  int i = blockIdx.x * blockDim.x + threadIdx.x;
  if (i < e) {
    int d = dst[i], s = src[i];
    int pos = row_ptr[d] + atomicAdd(&cursor[d], 1);
    csr_src[pos] = s;
    csr_norm[pos] = dinv[s] * dinv[d];
  }
}

// C[M,256] = A[M,K] @ W[K,256]; all f32.
// 128x128 tile, BK=16, 256 threads, 8x8 per thread.
__global__ __launch_bounds__(256, 2) void k_gemm(const float* __restrict__ A,
                                                 const float* __restrict__ W,
                                                 float* __restrict__ C, int M, int K) {
  __shared__ float As[16][132];  // [k][m], padded
  __shared__ float Bs[16][132];  // [k][n], padded
  const int tid = threadIdx.x;
  const int tx = tid & 15, ty = tid >> 4;
  const int n0 = blockIdx.x * 128;
  const int m0 = blockIdx.y * 128;
  float acc[8][8];
#pragma unroll
  for (int i = 0; i < 8; ++i)
#pragma unroll
    for (int j = 0; j < 8; ++j) acc[i][j] = 0.f;

  for (int k0 = 0; k0 < K; k0 += 16) {
    {
      int r = tid >> 2;
      int kc = (tid & 3) * 4;
#pragma unroll
      for (int h = 0; h < 2; ++h) {
        int row = r + h * 64;
        int grow = m0 + row;
        float4 a = make_float4(0.f, 0.f, 0.f, 0.f);
        if (grow < M) a = *(const float4*)(A + (size_t)grow * K + k0 + kc);
        As[kc + 0][row] = a.x;
        As[kc + 1][row] = a.y;
        As[kc + 2][row] = a.z;
        As[kc + 3][row] = a.w;
      }
    }
    {
      int kk = tid >> 4;
      int cc = (tid & 15) * 8;
      const float* wp = W + (size_t)(k0 + kk) * 256 + n0 + cc;
      float4 b0 = *(const float4*)(wp);
      float4 b1 = *(const float4*)(wp + 4);
      *(float4*)&Bs[kk][cc] = b0;
      *(float4*)&Bs[kk][cc + 4] = b1;
    }
    __syncthreads();
#pragma unroll
    for (int k = 0; k < 16; ++k) {
      float a[8], b[8];
      *(float4*)&a[0] = *(const float4*)&As[k][ty * 8];
      *(float4*)&a[4] = *(const float4*)&As[k][ty * 8 + 4];
      *(float4*)&b[0] = *(const float4*)&Bs[k][tx * 8];
      *(float4*)&b[4] = *(const float4*)&Bs[k][tx * 8 + 4];
#pragma unroll
      for (int i = 0; i < 8; ++i)
#pragma unroll
        for (int j = 0; j < 8; ++j) acc[i][j] = fmaf(a[i], b[j], acc[i][j]);
    }
    __syncthreads();
  }
#pragma unroll
  for (int i = 0; i < 8; ++i) {
    int grow = m0 + ty * 8 + i;
    if (grow < M) {
      float4 c0, c1;
      c0.x = acc[i][0]; c0.y = acc[i][1]; c0.z = acc[i][2]; c0.w = acc[i][3];
      c1.x = acc[i][4]; c1.y = acc[i][5]; c1.z = acc[i][6]; c1.w = acc[i][7];
      *(float4*)(C + (size_t)grow * 256 + n0 + tx * 8) = c0;
      *(float4*)(C + (size_t)grow * 256 + n0 + tx * 8 + 4) = c1;
    }
  }
}

// one wave per node; 64 lanes x float4 = 256 channels
template<bool RELU>
__global__ __launch_bounds__(256) void k_agg(const float* __restrict__ h,
                                             const float* __restrict__ dinv,
                                             const int* __restrict__ row_ptr,
                                             const int* __restrict__ csr_src,
                                             const float* __restrict__ csr_norm,
                                             const float* __restrict__ bias,
                                             float* __restrict__ out, int n) {
  int node = blockIdx.x * 4 + (threadIdx.x >> 6);
  if (node >= n) return;
  int lane = threadIdx.x & 63;
  int c = lane * 4;
  float di = dinv[node];
  float s2 = di * di;
  float4 hv = *(const float4*)(h + (size_t)node * 256 + c);
  float4 bv = *(const float4*)(bias + c);
  float4 acc;
  acc.x = fmaf(s2, hv.x, bv.x);
  acc.y = fmaf(s2, hv.y, bv.y);
  acc.z = fmaf(s2, hv.z, bv.z);
  acc.w = fmaf(s2, hv.w, bv.w);
  int p0 = row_ptr[node], p1 = row_ptr[node + 1];
  for (int p = p0; p < p1; ++p) {
    int s = csr_src[p];
    float w = csr_norm[p];
    float4 v = *(const float4*)(h + (size_t)s * 256 + c);
    acc.x = fmaf(w, v.x, acc.x);
    acc.y = fmaf(w, v.y, acc.y);
    acc.z = fmaf(w, v.z, acc.z);
    acc.w = fmaf(w, v.w, acc.w);
  }
  if (RELU) {
    acc.x = fmaxf(acc.x, 0.f); acc.y = fmaxf(acc.y, 0.f);
    acc.z = fmaxf(acc.z, 0.f); acc.w = fmaxf(acc.w, 0.f);
  }
  *(float4*)(out + (size_t)node * 256 + c) = acc;
}

extern "C" void kernel_launch(void* const* d_in, const int* in_sizes, int n_in,
                              void* d_out, int out_size, void* d_ws, size_t ws_size,
                              hipStream_t stream) {
  const float* x  = (const float*)d_in[0];
  const int*   ei = (const int*)d_in[1];
  const float* W1 = (const float*)d_in[2];
  const float* b1 = (const float*)d_in[3];
  const float* W2 = (const float*)d_in[4];
  const float* b2 = (const float*)d_in[5];
  const float* W3 = (const float*)d_in[6];
  const float* b3 = (const float*)d_in[7];
  float* out = (float*)d_out;
  (void)in_sizes; (void)n_in; (void)out_size; (void)ws_size;

  char* ws = (char*)d_ws;
  size_t off = 0;
  auto alloc = [&](size_t bytes) -> void* {
    void* p = (void*)(ws + off);
    off += (bytes + 255) & ~(size_t)255;
    return p;
  };
  float* dinv    = (float*)alloc((size_t)NNODES * 4);
  int*   deg     = (int*)alloc((size_t)NNODES * 4);
  int*   row_ptr = (int*)alloc((size_t)(NNODES + 1) * 4);
  int*   csr_src = (int*)alloc((size_t)NEDGES * 4);
  float* csr_nrm = (float*)alloc((size_t)NEDGES * 4);
  float* bufA    = (float*)alloc((size_t)NNODES * 256 * 4);
  float* bufB    = (float*)alloc((size_t)NNODES * 256 * 4);

  const int* e_src = ei;
  const int* e_dst = ei + NEDGES;

  const int tb = 256;
  k_zero_i32<<<(NNODES + tb - 1) / tb, tb, 0, stream>>>(deg, NNODES);
  k_hist<<<(NEDGES + tb - 1) / tb, tb, 0, stream>>>(e_dst, deg, NEDGES);
  k_dinv<<<(NNODES + tb - 1) / tb, tb, 0, stream>>>(deg, dinv, NNODES);
  k_scan<<<1, 1024, 0, stream>>>(deg, row_ptr, NNODES);
  k_zero_i32<<<(NNODES + tb - 1) / tb, tb, 0, stream>>>(deg, NNODES);
  k_fill<<<(NEDGES + tb - 1) / tb, tb, 0, stream>>>(e_src, e_dst, dinv, row_ptr, deg,
                                                    csr_src, csr_nrm, NEDGES);

  dim3 ggrid(2, (NNODES + 127) / 128);
  k_gemm<<<ggrid, 256, 0, stream>>>(x, W1, bufA, NNODES, DIN);
  k_agg<true><<<(NNODES + 3) / 4, 256, 0, stream>>>(bufA, dinv, row_ptr, csr_src,
                                                    csr_nrm, b1, bufB, NNODES);
  k_gemm<<<ggrid, 256, 0, stream>>>(bufB, W2, bufA, NNODES, DHID);
  k_agg<true><<<(NNODES + 3) / 4, 256, 0, stream>>>(bufA, dinv, row_ptr, csr_src,
                                                    csr_nrm, b2, bufB, NNODES);
  k_gemm<<<ggrid, 256, 0, stream>>>(bufB, W3, bufA, NNODES, DHID);
  k_agg<false><<<(NNODES + 3) / 4, 256, 0, stream>>>(bufA, dinv, row_ptr, csr_src,
                                                     csr_nrm, b3, out, NNODES);
}